// Round 6
// baseline (215.282 us; speedup 1.0000x reference)
//
#include <hip/hip_runtime.h>
#include <hip/hip_bf16.h>

typedef short s8v __attribute__((ext_vector_type(8)));
typedef float f4v __attribute__((ext_vector_type(4)));
typedef unsigned short u16;
typedef unsigned int u32;

#define PI_HALF 1.57079632679489662f

// ---------------------------------------------------------------------------
// Prep: repack weights into d_ws.
//   w3f: bf16 fragment-packed W3: [(ntg 16)][(kk 8)][(lane 64)][(j 8)]
//        lane -> (n = ntg*16 + (lane&15), k = kk*32 + (lane>>4)*8 + j)
//   w4f: same packing for W4 (ntg 0..31)
//   w1t: f32 [256][8], w1t[k*8+j] = W1[j][k]
//   w2c: f32 [256][8], w2c[k*8+q] = W2[k][q]   (only cols 0..7 are live)
// ---------------------------------------------------------------------------
__global__ void prep_kernel(const float* __restrict__ W1,
                            const float* __restrict__ W2,
                            const float* __restrict__ W3,
                            const float* __restrict__ W4,
                            u16* __restrict__ w3f,
                            u16* __restrict__ w4f,
                            float* __restrict__ w1t,
                            float* __restrict__ w2c) {
  int i = blockIdx.x * 256 + threadIdx.x;
  if (i < 65536) {
    int j = i & 7, lane = (i >> 3) & 63, kk = (i >> 9) & 7, ntg = i >> 12;
    int k = kk * 32 + (lane >> 4) * 8 + j;
    int n = ntg * 16 + (lane & 15);
    __hip_bfloat16 v = __float2bfloat16(W3[k * 256 + n]);
    w3f[i] = *(u16*)&v;
  } else if (i < 65536 + 131072) {
    int t = i - 65536;
    int j = t & 7, lane = (t >> 3) & 63, kk = (t >> 9) & 7, ntg = t >> 12;
    int k = kk * 32 + (lane >> 4) * 8 + j;
    int n = ntg * 16 + (lane & 15);
    __hip_bfloat16 v = __float2bfloat16(W4[k * 512 + n]);
    w4f[t] = *(u16*)&v;
  } else if (i < 65536 + 131072 + 2048) {
    int t = i - (65536 + 131072);
    int k = t >> 3, j = t & 7;
    w1t[t] = W1[j * 256 + k];
  } else if (i < 65536 + 131072 + 4096) {
    int t = i - (65536 + 131072 + 2048);
    int k = t >> 3, q = t & 7;
    w2c[t] = W2[k * 256 + q];
  }
}

// ---------------------------------------------------------------------------
// Fused kernel: 128 rows/block, 512 threads (8 waves, 2x4 wave grid).
// __launch_bounds__(512,2): min-waves=2 -> VGPR cap 256. EMPIRICAL (R1 vs
// R2-R5): min_waves=4 (cap 128) makes the compiler emit the VGPR=64 spill
// codegen (+92MB fetch / +182MB write of scratch traffic); min_waves=2 gave
// the clean 96-VGPR build (FETCH 9MB / WRITE 268MB). Runtime residency (2
// blocks/CU) is resource-limited, not bound-limited: 2x64KB LDS <= 160KB,
// 4 waves/SIMD x 96 VGPR <= 512.
// Phase 1 (threads 0..127, 1 thread/row, fp32, fully static indexing):
//   h = relu(x@W1+b1) streamed over k; e8 = h@W2[:,:8]+b2[:8]; relu;
//   state row = kron of (cos,sin) pairs -> bf16 -> LDS (XOR-swizzled).
// GEMM A: f = relu(state@W3+b3) via 16x16x32 bf16 MFMA, f overwrites LDS.
// GEMM B: out = f@W4+b4, fp32 stores.
// ---------------------------------------------------------------------------
__global__ __launch_bounds__(512, 2)
void fused_kernel(const float* __restrict__ x,
                  const float* __restrict__ b1v,
                  const float* __restrict__ b2v,
                  const float* __restrict__ b3v,
                  const float* __restrict__ b4v,
                  const u16* __restrict__ w3f,
                  const u16* __restrict__ w4f,
                  const float* __restrict__ w1t,
                  const float* __restrict__ w2c,
                  float* __restrict__ out, int B) {
  __shared__ alignas(16) u16 st[128 * 256];   // 64 KB: state tile, then f tile
  const int tid = threadIdx.x;
  const int row0 = blockIdx.x * 128;

  // ---------------- phase 1: rows -> quantum state (fp32) ----------------
  if (tid < 128) {
    const int r = row0 + tid;
    float xv[8];
    if (r < B) {
      const float4* xp = (const float4*)(x + (size_t)r * 8);
      float4 a = xp[0], b = xp[1];
      xv[0] = a.x; xv[1] = a.y; xv[2] = a.z; xv[3] = a.w;
      xv[4] = b.x; xv[5] = b.y; xv[6] = b.z; xv[7] = b.w;
    } else {
#pragma unroll
      for (int j = 0; j < 8; j++) xv[j] = 0.f;
    }
    float e[8];
#pragma unroll
    for (int q = 0; q < 8; q++) e[q] = b2v[q];
#pragma unroll 4
    for (int k = 0; k < 256; k++) {
      const float4* wp = (const float4*)(w1t + k * 8);   // uniform -> s_load
      float4 wa = wp[0], wb = wp[1];
      float h = b1v[k];
      h = fmaf(xv[0], wa.x, h); h = fmaf(xv[1], wa.y, h);
      h = fmaf(xv[2], wa.z, h); h = fmaf(xv[3], wa.w, h);
      h = fmaf(xv[4], wb.x, h); h = fmaf(xv[5], wb.y, h);
      h = fmaf(xv[6], wb.z, h); h = fmaf(xv[7], wb.w, h);
      h = fmaxf(h, 0.f);
      const float4* w2p = (const float4*)(w2c + k * 8);  // uniform (cols 0..7)
      float4 ya = w2p[0], yb = w2p[1];
      e[0] = fmaf(h, ya.x, e[0]); e[1] = fmaf(h, ya.y, e[1]);
      e[2] = fmaf(h, ya.z, e[2]); e[3] = fmaf(h, ya.w, e[3]);
      e[4] = fmaf(h, yb.x, e[4]); e[5] = fmaf(h, yb.y, e[5]);
      e[6] = fmaf(h, yb.z, e[6]); e[7] = fmaf(h, yb.w, e[7]);
    }
    float cc[8], ss[8];
#pragma unroll
    for (int q = 0; q < 8; q++) {
      float ang = fmaxf(e[q], 0.f) * PI_HALF;   // relu(enc) * pi/2
      ss[q] = __sinf(ang);
      cc[q] = __cosf(ang);
    }
    // A16: qubits 0..3 (index j = b0*8+b1*4+b2*2+b3), L16: qubits 4..7
    float A16[16], L16[16];
    {
      float t4[4], t8[8];
      t4[0] = cc[0] * cc[1]; t4[1] = cc[0] * ss[1];
      t4[2] = ss[0] * cc[1]; t4[3] = ss[0] * ss[1];
#pragma unroll
      for (int j = 0; j < 4; j++) { t8[2*j] = t4[j] * cc[2]; t8[2*j+1] = t4[j] * ss[2]; }
#pragma unroll
      for (int j = 0; j < 8; j++) { A16[2*j] = t8[j] * cc[3]; A16[2*j+1] = t8[j] * ss[3]; }
      t4[0] = cc[4] * cc[5]; t4[1] = cc[4] * ss[5];
      t4[2] = ss[4] * cc[5]; t4[3] = ss[4] * ss[5];
#pragma unroll
      for (int j = 0; j < 4; j++) { t8[2*j] = t4[j] * cc[6]; t8[2*j+1] = t4[j] * ss[6]; }
#pragma unroll
      for (int j = 0; j < 8; j++) { L16[2*j] = t8[j] * cc[7]; L16[2*j+1] = t8[j] * ss[7]; }
    }
    // write state row (256 bf16) to LDS, swizzled, 16B at a time
#pragma unroll
    for (int g = 0; g < 32; g++) {
      float ah = A16[g >> 1];
      const int lo0 = (g & 1) << 3;
      union { u16 h8[8]; uint4 u4; } pk;
#pragma unroll
      for (int j = 0; j < 8; j++) {
        __hip_bfloat16 bv = __float2bfloat16(ah * L16[lo0 + j]);
        pk.h8[j] = *(u16*)&bv;
      }
      u32 byte = (u32)(tid * 512 + g * 16) ^ (u32)((tid & 7) << 4);
      *(uint4*)((char*)st + byte) = pk.u4;
    }
  }
  __syncthreads();

  // ---------------- wave/tile decomposition ----------------
  const int lane = tid & 63;
  const int wid  = tid >> 6;      // 0..7
  const int wm   = wid >> 2;      // 0..1  -> 64-row half
  const int wn   = wid & 3;       // 0..3  -> N slice
  const int lr   = lane & 15;
  const int lg   = lane >> 4;
  const int m0   = wm * 64;

  // ---------------- GEMM A: f = relu(state @ W3 + b3) ----------------
  f4v accA[4][4];                 // [nt][mt]
#pragma unroll
  for (int nt = 0; nt < 4; nt++)
#pragma unroll
    for (int mt = 0; mt < 4; mt++) accA[nt][mt] = (f4v){0.f, 0.f, 0.f, 0.f};

  for (int kk = 0; kk < 8; kk++) {
    s8v a[4];
#pragma unroll
    for (int mt = 0; mt < 4; mt++) {
      int row = m0 + mt * 16 + lr;
      u32 byte = (u32)(row * 512 + kk * 64 + lg * 16) ^ (u32)((row & 7) << 4);
      a[mt] = *(const s8v*)((const char*)st + byte);
    }
#pragma unroll
    for (int nt = 0; nt < 4; nt++) {
      int ntg = wn * 4 + nt;
      s8v b = ((const s8v*)w3f)[(ntg * 8 + kk) * 64 + lane];
#pragma unroll
      for (int mt = 0; mt < 4; mt++)
        accA[nt][mt] = __builtin_amdgcn_mfma_f32_16x16x32_bf16(a[mt], b, accA[nt][mt], 0, 0, 0);
    }
  }
  __syncthreads();                 // all state reads complete before overwrite

  // f (bf16) overwrites state tile in place
#pragma unroll
  for (int nt = 0; nt < 4; nt++) {
    int col = wn * 64 + nt * 16 + lr;
    float bias = b3v[col];
#pragma unroll
    for (int mt = 0; mt < 4; mt++) {
#pragma unroll
      for (int i = 0; i < 4; i++) {
        int row = m0 + mt * 16 + lg * 4 + i;
        float v = fmaxf(accA[nt][mt][i] + bias, 0.f);
        __hip_bfloat16 bv = __float2bfloat16(v);
        u32 byte = (u32)(row * 512 + col * 2) ^ (u32)((row & 7) << 4);
        *(u16*)((char*)st + byte) = *(u16*)&bv;
      }
    }
  }
  __syncthreads();

  // ---------------- GEMM B: out = f @ W4 + b4 (two 64-col chunks) -------
#pragma unroll 1
  for (int nh = 0; nh < 2; nh++) {
    const int nbase = wn * 128 + nh * 64;
    f4v accB[4][4];
#pragma unroll
    for (int nt = 0; nt < 4; nt++)
#pragma unroll
      for (int mt = 0; mt < 4; mt++) accB[nt][mt] = (f4v){0.f, 0.f, 0.f, 0.f};

    for (int kk = 0; kk < 8; kk++) {
      s8v a[4];
#pragma unroll
      for (int mt = 0; mt < 4; mt++) {
        int row = m0 + mt * 16 + lr;
        u32 byte = (u32)(row * 512 + kk * 64 + lg * 16) ^ (u32)((row & 7) << 4);
        a[mt] = *(const s8v*)((const char*)st + byte);
      }
#pragma unroll
      for (int nt = 0; nt < 4; nt++) {
        int ntg = (nbase >> 4) + nt;
        s8v b = ((const s8v*)w4f)[(ntg * 8 + kk) * 64 + lane];
#pragma unroll
        for (int mt = 0; mt < 4; mt++)
          accB[nt][mt] = __builtin_amdgcn_mfma_f32_16x16x32_bf16(a[mt], b, accB[nt][mt], 0, 0, 0);
      }
    }
    // store fp32 + bias
#pragma unroll
    for (int nt = 0; nt < 4; nt++) {
      int col = nbase + nt * 16 + lr;
      float bias = b4v[col];
#pragma unroll
      for (int mt = 0; mt < 4; mt++) {
        int rowg = row0 + m0 + mt * 16 + lg * 4;
        if (rowg + 3 < B) {
          float* op = out + (size_t)rowg * 512 + col;
          op[0]    = accB[nt][mt][0] + bias;
          op[512]  = accB[nt][mt][1] + bias;
          op[1024] = accB[nt][mt][2] + bias;
          op[1536] = accB[nt][mt][3] + bias;
        } else {
#pragma unroll
          for (int i = 0; i < 4; i++)
            if (rowg + i < B) out[(size_t)(rowg + i) * 512 + col] = accB[nt][mt][i] + bias;
        }
      }
    }
  }
}

extern "C" void kernel_launch(void* const* d_in, const int* in_sizes, int n_in,
                              void* d_out, int out_size, void* d_ws, size_t ws_size,
                              hipStream_t stream) {
  const float* x  = (const float*)d_in[0];
  const float* W1 = (const float*)d_in[1];
  const float* b1 = (const float*)d_in[2];
  const float* W2 = (const float*)d_in[3];
  const float* b2 = (const float*)d_in[4];
  const float* W3 = (const float*)d_in[5];
  const float* b3 = (const float*)d_in[6];
  const float* W4 = (const float*)d_in[7];
  const float* b4 = (const float*)d_in[8];
  float* out = (float*)d_out;
  const int B = in_sizes[0] / 8;

  u16*   w3f = (u16*)d_ws;                                        // 128 KB
  u16*   w4f = (u16*)((char*)d_ws + 131072);                      // 256 KB
  float* w1t = (float*)((char*)d_ws + 131072 + 262144);           //   8 KB
  float* w2c = (float*)((char*)d_ws + 131072 + 262144 + 8192);    //   8 KB

  prep_kernel<<<784, 256, 0, stream>>>(W1, W2, W3, W4, w3f, w4f, w1t, w2c);

  const int grid = (B + 127) / 128;
  fused_kernel<<<grid, 512, 0, stream>>>(x, b1, b2, b3, b4, w3f, w4f, w1t, w2c, out, B);
}

// Round 7
// 181.472 us; speedup vs baseline: 1.1863x; 1.1863x over previous
//
#include <hip/hip_runtime.h>
#include <hip/hip_bf16.h>

typedef short s8v __attribute__((ext_vector_type(8)));
typedef float f4v __attribute__((ext_vector_type(4)));
typedef unsigned short u16;
typedef unsigned int u32;

#define PI_HALF 1.57079632679489662f

// ---------------------------------------------------------------------------
// Prep: repack weights into d_ws.
//   w3f: bf16 fragment-packed W3: [(ntg 16)][(kk 8)][(lane 64)][(j 8)]
//        lane -> (n = ntg*16 + (lane&15), k = kk*32 + (lane>>4)*8 + j)
//   w4f: same packing for W4 (ntg 0..31)
//   w1t: f32 [256][8], w1t[k*8+j] = W1[j][k]
//   w2c: f32 [256][8], w2c[k*8+q] = W2[k][q]   (only cols 0..7 are live)
// ---------------------------------------------------------------------------
__global__ void prep_kernel(const float* __restrict__ W1,
                            const float* __restrict__ W2,
                            const float* __restrict__ W3,
                            const float* __restrict__ W4,
                            u16* __restrict__ w3f,
                            u16* __restrict__ w4f,
                            float* __restrict__ w1t,
                            float* __restrict__ w2c) {
  int i = blockIdx.x * 256 + threadIdx.x;
  if (i < 65536) {
    int j = i & 7, lane = (i >> 3) & 63, kk = (i >> 9) & 7, ntg = i >> 12;
    int k = kk * 32 + (lane >> 4) * 8 + j;
    int n = ntg * 16 + (lane & 15);
    __hip_bfloat16 v = __float2bfloat16(W3[k * 256 + n]);
    w3f[i] = *(u16*)&v;
  } else if (i < 65536 + 131072) {
    int t = i - 65536;
    int j = t & 7, lane = (t >> 3) & 63, kk = (t >> 9) & 7, ntg = t >> 12;
    int k = kk * 32 + (lane >> 4) * 8 + j;
    int n = ntg * 16 + (lane & 15);
    __hip_bfloat16 v = __float2bfloat16(W4[k * 512 + n]);
    w4f[t] = *(u16*)&v;
  } else if (i < 65536 + 131072 + 2048) {
    int t = i - (65536 + 131072);
    int k = t >> 3, j = t & 7;
    w1t[t] = W1[j * 256 + k];
  } else if (i < 65536 + 131072 + 4096) {
    int t = i - (65536 + 131072 + 2048);
    int k = t >> 3, q = t & 7;
    w2c[t] = W2[k * 256 + q];
  }
}

// ---------------------------------------------------------------------------
// Fused kernel: 64 rows/block, 256 threads (4 waves), 32 KB LDS.
// REGISTER/OCCUPANCY MODEL (R1-R6 evidence): clean codegen costs ~96 arch
// VGPR + 64 AGPR (GEMM-A acc) = 160 regs/wave -> 3 waves/SIMD. A 4-wave
// block then gets 3 blocks/CU (12 waves, 96KB LDS <= 160KB) -- vs R6's
// 8-wave block that fit only once. min_waves=2 keeps the allocator
// unconstrained (min_waves=4 provably forces ~90MB/launch scratch spills).
// Phase 1 (threads 0..63, 1 thread/row, fp32, fully static indexing):
//   h = relu(x@W1+b1) streamed; e8 = h@W2[:,:8]+b2[:8]; relu;
//   state row = kron of (cos,sin) -> bf16 -> LDS (XOR-swizzled).
// GEMM A: f = relu(state@W3+b3), 16x16x32 bf16 MFMA, acc 4x4 (64 AGPR),
//   f overwrites state LDS in place after a barrier.
// GEMM B: out = f@W4+b4 in FOUR 32-col chunks (acc 2x4 = 32 AGPR).
// ---------------------------------------------------------------------------
__global__ __launch_bounds__(256, 2)
void fused_kernel(const float* __restrict__ x,
                  const float* __restrict__ b1v,
                  const float* __restrict__ b2v,
                  const float* __restrict__ b3v,
                  const float* __restrict__ b4v,
                  const u16* __restrict__ w3f,
                  const u16* __restrict__ w4f,
                  const float* __restrict__ w1t,
                  const float* __restrict__ w2c,
                  float* __restrict__ out, int B) {
  __shared__ alignas(16) u16 st[64 * 256];   // 32 KB: state tile, then f tile
  const int tid = threadIdx.x;
  const int row0 = blockIdx.x * 64;

  // ---------------- phase 1: rows -> quantum state (fp32) ----------------
  if (tid < 64) {
    const int r = row0 + tid;
    float xv[8];
    if (r < B) {
      const float4* xp = (const float4*)(x + (size_t)r * 8);
      float4 a = xp[0], b = xp[1];
      xv[0] = a.x; xv[1] = a.y; xv[2] = a.z; xv[3] = a.w;
      xv[4] = b.x; xv[5] = b.y; xv[6] = b.z; xv[7] = b.w;
    } else {
#pragma unroll
      for (int j = 0; j < 8; j++) xv[j] = 0.f;
    }
    float e[8];
#pragma unroll
    for (int q = 0; q < 8; q++) e[q] = b2v[q];
#pragma unroll 4
    for (int k = 0; k < 256; k++) {
      const float4* wp = (const float4*)(w1t + k * 8);   // uniform -> s_load
      float4 wa = wp[0], wb = wp[1];
      float h = b1v[k];
      h = fmaf(xv[0], wa.x, h); h = fmaf(xv[1], wa.y, h);
      h = fmaf(xv[2], wa.z, h); h = fmaf(xv[3], wa.w, h);
      h = fmaf(xv[4], wb.x, h); h = fmaf(xv[5], wb.y, h);
      h = fmaf(xv[6], wb.z, h); h = fmaf(xv[7], wb.w, h);
      h = fmaxf(h, 0.f);
      const float4* w2p = (const float4*)(w2c + k * 8);  // uniform (cols 0..7)
      float4 ya = w2p[0], yb = w2p[1];
      e[0] = fmaf(h, ya.x, e[0]); e[1] = fmaf(h, ya.y, e[1]);
      e[2] = fmaf(h, ya.z, e[2]); e[3] = fmaf(h, ya.w, e[3]);
      e[4] = fmaf(h, yb.x, e[4]); e[5] = fmaf(h, yb.y, e[5]);
      e[6] = fmaf(h, yb.z, e[6]); e[7] = fmaf(h, yb.w, e[7]);
    }
    float cc[8], ss[8];
#pragma unroll
    for (int q = 0; q < 8; q++) {
      float ang = fmaxf(e[q], 0.f) * PI_HALF;   // relu(enc) * pi/2
      ss[q] = __sinf(ang);
      cc[q] = __cosf(ang);
    }
    // A16: qubits 0..3 (index j = b0*8+b1*4+b2*2+b3), L16: qubits 4..7
    float A16[16], L16[16];
    {
      float t4[4], t8[8];
      t4[0] = cc[0] * cc[1]; t4[1] = cc[0] * ss[1];
      t4[2] = ss[0] * cc[1]; t4[3] = ss[0] * ss[1];
#pragma unroll
      for (int j = 0; j < 4; j++) { t8[2*j] = t4[j] * cc[2]; t8[2*j+1] = t4[j] * ss[2]; }
#pragma unroll
      for (int j = 0; j < 8; j++) { A16[2*j] = t8[j] * cc[3]; A16[2*j+1] = t8[j] * ss[3]; }
      t4[0] = cc[4] * cc[5]; t4[1] = cc[4] * ss[5];
      t4[2] = ss[4] * cc[5]; t4[3] = ss[4] * ss[5];
#pragma unroll
      for (int j = 0; j < 4; j++) { t8[2*j] = t4[j] * cc[6]; t8[2*j+1] = t4[j] * ss[6]; }
#pragma unroll
      for (int j = 0; j < 8; j++) { L16[2*j] = t8[j] * cc[7]; L16[2*j+1] = t8[j] * ss[7]; }
    }
    // write state row (256 bf16) to LDS, swizzled, 16B at a time
#pragma unroll
    for (int g = 0; g < 32; g++) {
      float ah = A16[g >> 1];
      const int lo0 = (g & 1) << 3;
      union { u16 h8[8]; uint4 u4; } pk;
#pragma unroll
      for (int j = 0; j < 8; j++) {
        __hip_bfloat16 bv = __float2bfloat16(ah * L16[lo0 + j]);
        pk.h8[j] = *(u16*)&bv;
      }
      u32 byte = (u32)(tid * 512 + g * 16) ^ (u32)((tid & 7) << 4);
      *(uint4*)((char*)st + byte) = pk.u4;
    }
  }
  __syncthreads();

  // ---------------- wave/tile decomposition ----------------
  const int lane = tid & 63;
  const int wn   = tid >> 6;      // 0..3 -> N slice (all 64 rows per wave)
  const int lr   = lane & 15;
  const int lg   = lane >> 4;

  // ---------------- GEMM A: f = relu(state @ W3 + b3) ----------------
  f4v accA[4][4];                 // [nt][mt] -> 64 AGPR (held across barrier)
#pragma unroll
  for (int nt = 0; nt < 4; nt++)
#pragma unroll
    for (int mt = 0; mt < 4; mt++) accA[nt][mt] = (f4v){0.f, 0.f, 0.f, 0.f};

  for (int kk = 0; kk < 8; kk++) {
    s8v a[4];
#pragma unroll
    for (int mt = 0; mt < 4; mt++) {
      int row = mt * 16 + lr;
      u32 byte = (u32)(row * 512 + kk * 64 + lg * 16) ^ (u32)((row & 7) << 4);
      a[mt] = *(const s8v*)((const char*)st + byte);
    }
#pragma unroll
    for (int nt = 0; nt < 4; nt++) {
      int ntg = wn * 4 + nt;
      s8v b = ((const s8v*)w3f)[(ntg * 8 + kk) * 64 + lane];
#pragma unroll
      for (int mt = 0; mt < 4; mt++)
        accA[nt][mt] = __builtin_amdgcn_mfma_f32_16x16x32_bf16(a[mt], b, accA[nt][mt], 0, 0, 0);
    }
  }
  __syncthreads();                 // all state reads complete before overwrite

  // f (bf16) overwrites state tile in place
#pragma unroll
  for (int nt = 0; nt < 4; nt++) {
    int col = wn * 64 + nt * 16 + lr;
    float bias = b3v[col];
#pragma unroll
    for (int mt = 0; mt < 4; mt++) {
#pragma unroll
      for (int i = 0; i < 4; i++) {
        int row = mt * 16 + lg * 4 + i;
        float v = fmaxf(accA[nt][mt][i] + bias, 0.f);
        __hip_bfloat16 bv = __float2bfloat16(v);
        u32 byte = (u32)(row * 512 + col * 2) ^ (u32)((row & 7) << 4);
        *(u16*)((char*)st + byte) = *(u16*)&bv;
      }
    }
  }
  __syncthreads();

  // ---------------- GEMM B: out = f @ W4 + b4 (four 32-col chunks) ------
#pragma unroll 1
  for (int nh = 0; nh < 4; nh++) {
    const int nbase = wn * 128 + nh * 32;
    f4v accB[2][4];                // 32 AGPR per chunk
#pragma unroll
    for (int nt = 0; nt < 2; nt++)
#pragma unroll
      for (int mt = 0; mt < 4; mt++) accB[nt][mt] = (f4v){0.f, 0.f, 0.f, 0.f};

    for (int kk = 0; kk < 8; kk++) {
      s8v a[4];
#pragma unroll
      for (int mt = 0; mt < 4; mt++) {
        int row = mt * 16 + lr;
        u32 byte = (u32)(row * 512 + kk * 64 + lg * 16) ^ (u32)((row & 7) << 4);
        a[mt] = *(const s8v*)((const char*)st + byte);
      }
#pragma unroll
      for (int nt = 0; nt < 2; nt++) {
        int ntg = (nbase >> 4) + nt;
        s8v b = ((const s8v*)w4f)[(ntg * 8 + kk) * 64 + lane];
#pragma unroll
        for (int mt = 0; mt < 4; mt++)
          accB[nt][mt] = __builtin_amdgcn_mfma_f32_16x16x32_bf16(a[mt], b, accB[nt][mt], 0, 0, 0);
      }
    }
    // store fp32 + bias
#pragma unroll
    for (int nt = 0; nt < 2; nt++) {
      int col = nbase + nt * 16 + lr;
      float bias = b4v[col];
#pragma unroll
      for (int mt = 0; mt < 4; mt++) {
        int rowg = row0 + mt * 16 + lg * 4;
        if (rowg + 3 < B) {
          float* op = out + (size_t)rowg * 512 + col;
          op[0]    = accB[nt][mt][0] + bias;
          op[512]  = accB[nt][mt][1] + bias;
          op[1024] = accB[nt][mt][2] + bias;
          op[1536] = accB[nt][mt][3] + bias;
        } else {
#pragma unroll
          for (int i = 0; i < 4; i++)
            if (rowg + i < B) out[(size_t)(rowg + i) * 512 + col] = accB[nt][mt][i] + bias;
        }
      }
    }
  }
}

extern "C" void kernel_launch(void* const* d_in, const int* in_sizes, int n_in,
                              void* d_out, int out_size, void* d_ws, size_t ws_size,
                              hipStream_t stream) {
  const float* x  = (const float*)d_in[0];
  const float* W1 = (const float*)d_in[1];
  const float* b1 = (const float*)d_in[2];
  const float* W2 = (const float*)d_in[3];
  const float* b2 = (const float*)d_in[4];
  const float* W3 = (const float*)d_in[5];
  const float* b3 = (const float*)d_in[6];
  const float* W4 = (const float*)d_in[7];
  const float* b4 = (const float*)d_in[8];
  float* out = (float*)d_out;
  const int B = in_sizes[0] / 8;

  u16*   w3f = (u16*)d_ws;                                        // 128 KB
  u16*   w4f = (u16*)((char*)d_ws + 131072);                      // 256 KB
  float* w1t = (float*)((char*)d_ws + 131072 + 262144);           //   8 KB
  float* w2c = (float*)((char*)d_ws + 131072 + 262144 + 8192);    //   8 KB

  prep_kernel<<<784, 256, 0, stream>>>(W1, W2, W3, W4, w3f, w4f, w1t, w2c);

  const int grid = (B + 63) / 64;
  fused_kernel<<<grid, 256, 0, stream>>>(x, b1, b2, b3, b4, w3f, w4f, w1t, w2c, out, B);
}